// Round 2
// baseline (17148.972 us; speedup 1.0000x reference)
//
#include <hip/hip_runtime.h>
#include <math.h>

#define BB 16
#define CIN 64
#define TT 1024
#define DD 512
#define SS 512
#define NHEAD 8
#define HD 64
#define FFD 2048
#define NL 8
#define EPSV 1e-5f

typedef __attribute__((ext_vector_type(8))) short short8v;
typedef __attribute__((ext_vector_type(4))) float f32x4;

// ---------------- helpers ----------------
__device__ __forceinline__ unsigned short f2bf(float f) {
    unsigned u = __float_as_uint(f);
    u = (u + 0x7FFFu + ((u >> 16) & 1u)) >> 16;  // RNE
    return (unsigned short)u;
}

__device__ __forceinline__ void gload_lds16(const void* g, void* l) {
    __builtin_amdgcn_global_load_lds(
        (const __attribute__((address_space(1))) unsigned int*)g,
        (__attribute__((address_space(3))) unsigned int*)l, 16, 0, 0);
}

__device__ __forceinline__ float blk_sum256(float v, float* red) {
    int tid = threadIdx.x;
    red[tid] = v; __syncthreads();
    for (int off = 128; off > 0; off >>= 1) {
        if (tid < off) red[tid] += red[tid + off];
        __syncthreads();
    }
    float r = red[0]; __syncthreads();
    return r;
}

__device__ __forceinline__ float gelu_exact(float x) {
    return 0.5f * x * (1.0f + erff(x * 0.70710678118654752f));
}

// ---------------- fp32 -> bf16 conversions ----------------
// plain contiguous: n/4 threads, each one float4 -> ushort4
__global__ __launch_bounds__(256) void cvt_bf16_kernel(
        const float* __restrict__ in, unsigned short* __restrict__ out) {
    int i = blockIdx.x * 256 + threadIdx.x;
    float4 v = ((const float4*)in)[i];
    ushort4 o;
    o.x = f2bf(v.x); o.y = f2bf(v.y); o.z = f2bf(v.z); o.w = f2bf(v.w);
    ((ushort4*)out)[i] = o;
}

// segmented: nseg segments of seg_elems floats; segment s goes to
// out + s*out_stride (elems). Used to interleave Wq/Wk/Wv into [NL][1536][512].
__global__ __launch_bounds__(256) void cvt_bf16_seg_kernel(
        const float* __restrict__ in, unsigned short* __restrict__ out,
        int seg_elems4, int out_stride4) {
    int i = blockIdx.x * 256 + threadIdx.x;
    int seg = i / seg_elems4, off = i - seg * seg_elems4;
    float4 v = ((const float4*)in)[i];
    ushort4 o;
    o.x = f2bf(v.x); o.y = f2bf(v.y); o.z = f2bf(v.z); o.w = f2bf(v.w);
    ((ushort4*)out)[(size_t)seg * out_stride4 + off] = o;
}

// ---------------- conv0: Conv1d(64->512, k=15, s=2, p=7) ----------------
__global__ __launch_bounds__(256) void conv0_kernel(
        const float* __restrict__ x, const float* __restrict__ W,
        const float* __restrict__ bias, float* __restrict__ out) {
    int d = blockIdx.x, b = blockIdx.y;
    __shared__ float w[CIN * 15];
    int tid = threadIdx.x;
    for (int i = tid; i < CIN * 15; i += 256) w[i] = W[(size_t)d * CIN * 15 + i];
    __syncthreads();
    const float* xb = x + (size_t)b * CIN * TT;
    float bv = bias[d];
    #pragma unroll
    for (int j = 0; j < 2; ++j) {
        int s = tid + j * 256;
        int base = 2 * s - 7;
        float acc = bv;
        if (base >= 0 && base + 14 < TT) {
            for (int c = 0; c < CIN; ++c) {
                const float* xc = xb + (size_t)c * TT + base;
                const float* wc = w + c * 15;
                #pragma unroll
                for (int k = 0; k < 15; ++k) acc += xc[k] * wc[k];
            }
        } else {
            for (int c = 0; c < CIN; ++c) {
                const float* xc = xb + (size_t)c * TT;
                const float* wc = w + c * 15;
                #pragma unroll
                for (int k = 0; k < 15; ++k) {
                    int pos = base + k;
                    if (pos >= 0 && pos < TT) acc += xc[pos] * wc[k];
                }
            }
        }
        out[((size_t)b * DD + d) * SS + s] = acc;
    }
}

// ---------------- GroupNorm(2 ch/group) + GELU ----------------
// TRANSPOSE=1 additionally emits bf16 copy in [B,S,D] layout.
template <int TRANSPOSE>
__global__ __launch_bounds__(256) void gn_gelu_kernel(
        const float* __restrict__ in, const float* __restrict__ g,
        const float* __restrict__ bta, float* __restrict__ out,
        unsigned short* __restrict__ outb) {
    int grp = blockIdx.x, b = blockIdx.y;
    int c0 = grp * 2;
    __shared__ float red[256];
    int tid = threadIdx.x;
    const float* p0 = in + ((size_t)b * DD + c0) * SS;
    float v[4];
    float sum = 0.f;
    #pragma unroll
    for (int j = 0; j < 4; ++j) { v[j] = p0[tid + j * 256]; sum += v[j]; }
    float mean = blk_sum256(sum, red) * (1.0f / 1024.0f);
    float vs = 0.f;
    #pragma unroll
    for (int j = 0; j < 4; ++j) { float dlt = v[j] - mean; vs += dlt * dlt; }
    float var = blk_sum256(vs, red) * (1.0f / 1024.0f);
    float rs = rsqrtf(var + EPSV);
    #pragma unroll
    for (int j = 0; j < 4; ++j) {
        int f = tid + j * 256;
        int cl = f >> 9;
        int s = f & 511;
        float xn = (v[j] - mean) * rs * g[c0 + cl] + bta[c0 + cl];
        float ge = gelu_exact(xn);
        if (TRANSPOSE) {
            size_t idx = ((size_t)b * SS + s) * DD + (c0 + cl);
            out[idx] = ge;
            outb[idx] = f2bf(ge);
        } else {
            out[((size_t)b * DD + c0) * SS + f] = ge;
        }
    }
}

// ---------------- conv1: Conv1d(512->512, k=3, s=1, p=1) ----------------
__global__ __launch_bounds__(256) void conv1_kernel(
        const float* __restrict__ in, const float* __restrict__ W,
        const float* __restrict__ bias, float* __restrict__ out) {
    int d = blockIdx.x, b = blockIdx.y;
    __shared__ float w[DD * 3];
    int tid = threadIdx.x;
    for (int i = tid; i < DD * 3; i += 256) w[i] = W[(size_t)d * DD * 3 + i];
    __syncthreads();
    const float* xb = in + (size_t)b * DD * SS;
    float b0 = bias[d];
    #pragma unroll
    for (int j = 0; j < 2; ++j) {
        int s = tid + j * 256;
        float acc = b0;
        bool lo = (s > 0), hi = (s < SS - 1);
        for (int c = 0; c < DD; ++c) {
            const float* xc = xb + (size_t)c * SS;
            const float* wc = w + c * 3;
            if (lo) acc += xc[s - 1] * wc[0];
            acc += xc[s] * wc[1];
            if (hi) acc += xc[s + 1] * wc[2];
        }
        out[((size_t)b * DD + d) * SS + s] = acc;
    }
}

// ---------------- MFMA GEMM: C[M,N] = A[M,K] @ W[N,K]^T ----------------
// A, W bf16 (row-major, K contiguous). 128x128 tile, BK=64, 4 waves (2x2),
// 4x4 16x16x32 fragments per wave. global_load_lds (16B) with linear LDS
// dest + pre-swizzled global source; ds_read_b128 with matching XOR swizzle
// (slot ^= row&7) -> 2-way bank conflict (free).
// EPI: 0 none, 1 +bias, 2 +bias+relu. OUT_BF16: write bf16 instead of f32.
template <int EPI, int OUT_BF16>
__global__ __launch_bounds__(256) void gemm_mfma(
        const unsigned short* __restrict__ A, const unsigned short* __restrict__ W,
        const float* __restrict__ bias, void* __restrict__ Cout,
        int M, int N, int K) {
    __shared__ char smem[32768];
    char* sA = smem;            // [128 rows][8 slots of 16B] swizzled
    char* sB = smem + 16384;
    int tid = threadIdx.x;
    int bn = blockIdx.x * 128, bm = blockIdx.y * 128;
    int lane = tid & 63, wid = tid >> 6;
    int wm = wid >> 1, wn = wid & 1;
    int r = lane & 15, g = lane >> 4;
    f32x4 acc[4][4] = {};

    int srow = tid >> 3;        // 0..31
    int u = tid & 7;            // 16B slot within 128B row

    for (int kk = 0; kk < K; kk += 64) {
        #pragma unroll
        for (int i = 0; i < 4; ++i) {
            int row = i * 32 + srow;
            int u0 = u ^ (row & 7);   // inverse-swizzled source slot
            const char* ga = (const char*)(A + (size_t)(bm + row) * K + kk) + u0 * 16;
            gload_lds16(ga, sA + row * 128 + u * 16);
            const char* gb = (const char*)(W + (size_t)(bn + row) * K + kk) + u0 * 16;
            gload_lds16(gb, sB + row * 128 + u * 16);
        }
        __syncthreads();
        #pragma unroll
        for (int ks = 0; ks < 2; ++ks) {
            short8v af[4], bf[4];
            #pragma unroll
            for (int i = 0; i < 4; ++i) {
                int rowA = wm * 64 + i * 16 + r;
                af[i] = *(const short8v*)(sA + rowA * 128 + (((ks * 4 + g) ^ (rowA & 7)) * 16));
                int rowB = wn * 64 + i * 16 + r;
                bf[i] = *(const short8v*)(sB + rowB * 128 + (((ks * 4 + g) ^ (rowB & 7)) * 16));
            }
            #pragma unroll
            for (int i = 0; i < 4; ++i)
                #pragma unroll
                for (int j = 0; j < 4; ++j)
                    acc[i][j] = __builtin_amdgcn_mfma_f32_16x16x32_bf16(
                        af[i], bf[j], acc[i][j], 0, 0, 0);
        }
        __syncthreads();
    }

    float* Cf = (float*)Cout;
    unsigned short* Cb = (unsigned short*)Cout;
    #pragma unroll
    for (int i = 0; i < 4; ++i) {
        int row0 = bm + wm * 64 + i * 16 + g * 4;
        #pragma unroll
        for (int j = 0; j < 4; ++j) {
            int col = bn + wn * 64 + j * 16 + r;
            float bval = (EPI >= 1) ? bias[col] : 0.f;
            #pragma unroll
            for (int e = 0; e < 4; ++e) {
                float v = acc[i][j][e] + bval;
                if (EPI == 2) v = fmaxf(v, 0.f);
                if (OUT_BF16) Cb[(size_t)(row0 + e) * N + col] = f2bf(v);
                else          Cf[(size_t)(row0 + e) * N + col] = v;
            }
        }
    }
}

// ---------------- attention (fp32, fused-QKV input, bf16 out) ----------
// QKV [B*S, 1536] fp32: q at +0, k at +512, v at +1024. O bf16 [B*S, 512].
#define QKVS 1536
__global__ __launch_bounds__(256) void attn_kernel(
        const float* __restrict__ QKV, unsigned short* __restrict__ O) {
    int q = blockIdx.x, hh = blockIdx.y, b = blockIdx.z;
    int tid = threadIdx.x;
    __shared__ float p[SS];
    __shared__ float red[256];
    __shared__ float qv[HD];
    const float* qrow = QKV + (size_t)(b * SS + q) * QKVS + hh * HD;
    if (tid < HD) qv[tid] = qrow[tid];
    __syncthreads();
    #pragma unroll
    for (int j = 0; j < 2; ++j) {
        int kk = tid + j * 256;
        const float* krow = QKV + (size_t)(b * SS + kk) * QKVS + 512 + hh * HD;
        float acc = 0.f;
        #pragma unroll 8
        for (int dd = 0; dd < HD; ++dd) acc += qv[dd] * krow[dd];
        p[kk] = acc * 0.125f;
    }
    __syncthreads();
    float m = fmaxf(p[tid], p[tid + 256]);
    red[tid] = m; __syncthreads();
    for (int off = 128; off > 0; off >>= 1) {
        if (tid < off) red[tid] = fmaxf(red[tid], red[tid + off]);
        __syncthreads();
    }
    m = red[0]; __syncthreads();
    float psum = 0.f;
    #pragma unroll
    for (int j = 0; j < 2; ++j) {
        int kk = tid + j * 256;
        float e = expf(p[kk] - m);
        p[kk] = e;
        psum += e;
    }
    float ssum = blk_sum256(psum, red);
    float inv = 1.0f / ssum;
    int dd = tid & 63, seg = tid >> 6;
    float acc = 0.f;
    const float* vb = QKV + (size_t)b * SS * QKVS + 1024 + hh * HD + dd;
    for (int kk = seg * 128; kk < seg * 128 + 128; ++kk)
        acc += p[kk] * vb[(size_t)kk * QKVS];
    red[tid] = acc; __syncthreads();
    if (tid < 64) {
        float o = (red[tid] + red[tid + 64] + red[tid + 128] + red[tid + 192]) * inv;
        O[((size_t)(b * SS + q) * DD) + hh * HD + tid] = f2bf(o);
    }
}

// ---------------- fused add + LayerNorm, dual fp32+bf16 output ----------
__global__ __launch_bounds__(256) void add_ln_kernel(
        const float* __restrict__ A, const float* __restrict__ R,
        const float* __restrict__ g, const float* __restrict__ bta,
        float* __restrict__ out, unsigned short* __restrict__ outb) {
    int row = blockIdx.x;
    int tid = threadIdx.x;
    __shared__ float red[256];
    const float* a = A + (size_t)row * DD;
    const float* r = R + (size_t)row * DD;
    float x0 = a[tid] + r[tid];
    float x1 = a[tid + 256] + r[tid + 256];
    float mean = blk_sum256(x0 + x1, red) * (1.0f / DD);
    float d0 = x0 - mean, d1 = x1 - mean;
    float var = blk_sum256(d0 * d0 + d1 * d1, red) * (1.0f / DD);
    float rs = rsqrtf(var + EPSV);
    float y0 = d0 * rs * g[tid] + bta[tid];
    float y1 = d1 * rs * g[tid + 256] + bta[tid + 256];
    size_t o0 = (size_t)row * DD + tid;
    out[o0] = y0; out[o0 + 256] = y1;
    outb[o0] = f2bf(y0); outb[o0 + 256] = f2bf(y1);
}

// ---------------- deconv decoder ----------------
__global__ __launch_bounds__(256) void deconv_kernel(
        const float* __restrict__ Hbsd, const float* __restrict__ Wd,
        const float* __restrict__ bd, float* __restrict__ Y) {
    int co = blockIdx.x, b = blockIdx.y;
    __shared__ float w[DD * 3];
    int tid = threadIdx.x;
    for (int i = tid; i < DD * 3; i += 256) {
        int ci = i / 3, k = i % 3;
        w[i] = Wd[(size_t)ci * (CIN * 3) + co * 3 + k];
    }
    __syncthreads();
    float bv = bd[co];
    #pragma unroll
    for (int j = 0; j < 4; ++j) {
        int t = tid + j * 256;
        float acc = bv;
        if ((t & 1) == 0) {
            int s = t >> 1;
            const float* xr = Hbsd + ((size_t)b * SS + s) * DD;
            for (int ci = 0; ci < DD; ++ci) acc += xr[ci] * w[ci * 3 + 1];
        } else {
            int s0 = (t + 1) >> 1;
            int s1 = (t - 1) >> 1;
            if (s0 < SS) {
                const float* xr = Hbsd + ((size_t)b * SS + s0) * DD;
                for (int ci = 0; ci < DD; ++ci) acc += xr[ci] * w[ci * 3 + 0];
            }
            const float* xr1 = Hbsd + ((size_t)b * SS + s1) * DD;
            for (int ci = 0; ci < DD; ++ci) acc += xr1[ci] * w[ci * 3 + 2];
        }
        Y[((size_t)b * CIN + co) * TT + t] = acc;
    }
}

// ---------------- host launch ----------------
extern "C" void kernel_launch(void* const* d_in, const int* in_sizes, int n_in,
                              void* d_out, int out_size, void* d_ws, size_t ws_size,
                              hipStream_t stream) {
    const float* x      = (const float*)d_in[0];
    const float* convW0 = (const float*)d_in[1];
    const float* convb0 = (const float*)d_in[2];
    const float* gn0_g  = (const float*)d_in[3];
    const float* gn0_b  = (const float*)d_in[4];
    const float* convW1 = (const float*)d_in[5];
    const float* convb1 = (const float*)d_in[6];
    const float* gn1_g  = (const float*)d_in[7];
    const float* gn1_b  = (const float*)d_in[8];
    const float* Wq     = (const float*)d_in[9];
    const float* Wk     = (const float*)d_in[10];
    const float* Wv     = (const float*)d_in[11];
    const float* Wo     = (const float*)d_in[12];
    const float* W1     = (const float*)d_in[13];
    const float* b1     = (const float*)d_in[14];
    const float* W2     = (const float*)d_in[15];
    const float* b2     = (const float*)d_in[16];
    const float* ln1_g  = (const float*)d_in[17];
    const float* ln1_b  = (const float*)d_in[18];
    const float* ln2_g  = (const float*)d_in[19];
    const float* ln2_b  = (const float*)d_in[20];
    const float* Wd     = (const float*)d_in[21];
    const float* bd     = (const float*)d_in[22];

    const int M = BB * SS;                       // 8192
    const size_t NBUF = (size_t)M * DD;          // 4,194,304

    // ---- workspace layout (bytes) ----
    char* p = (char*)d_ws;
    float* h            = (float*)p;          p += NBUF * 4;                 // 16MB
    float* bqkv         = (float*)p;          p += (size_t)M * QKVS * 4;    // 48MB
    unsigned short* hb  = (unsigned short*)p; p += NBUF * 2;                 // 8MB
    unsigned short* bab = (unsigned short*)p; p += NBUF * 2;                 // 8MB
    unsigned short* hkb = (unsigned short*)p; p += NBUF * 2;                 // 8MB
    unsigned short* ffb = (unsigned short*)p; p += (size_t)M * FFD * 2;     // 32MB
    unsigned short* wqkvb = (unsigned short*)p; p += (size_t)NL * QKVS * DD * 2; // 25MB
    unsigned short* wob = (unsigned short*)p; p += (size_t)NL * DD * DD * 2;     // 8MB
    unsigned short* w1b = (unsigned short*)p; p += (size_t)NL * FFD * DD * 2;    // 16MB
    unsigned short* w2b = (unsigned short*)p; p += (size_t)NL * DD * FFD * 2;    // 16MB
    // fp32 scratch reuse of bqkv after attention consumes it:
    float* bo  = bqkv;                 // [M,512] O-proj out
    float* hk  = bqkv + NBUF;          // [M,512] post-LN1
    float* bf2 = bqkv + 2 * NBUF;      // [M,512] FF2 out

    // ---- weight conversion (bf16) ----
    {
        int seg4 = DD * DD / 4;                  // per-layer Wq chunk in float4s
        int ostr4 = QKVS * DD / 4;               // per-layer fused-QKV stride
        int blks = NL * seg4 / 256;
        cvt_bf16_seg_kernel<<<blks, 256, 0, stream>>>(Wq, wqkvb, seg4, ostr4);
        cvt_bf16_seg_kernel<<<blks, 256, 0, stream>>>(Wk, wqkvb + (size_t)DD * DD, seg4, ostr4);
        cvt_bf16_seg_kernel<<<blks, 256, 0, stream>>>(Wv, wqkvb + (size_t)2 * DD * DD, seg4, ostr4);
        cvt_bf16_kernel<<<NL * DD * DD / 1024, 256, 0, stream>>>(Wo, wob);
        cvt_bf16_kernel<<<NL * FFD * DD / 1024, 256, 0, stream>>>(W1, w1b);
        cvt_bf16_kernel<<<NL * DD * FFD / 1024, 256, 0, stream>>>(W2, w2b);
    }

    // ---- conv encoder (fp32) ----
    float* c0out = bqkv;               // scratch before transformer
    float* c1out = bqkv + NBUF;
    conv0_kernel<<<dim3(DD, BB), 256, 0, stream>>>(x, convW0, convb0, c0out);
    gn_gelu_kernel<0><<<dim3(DD / 2, BB), 256, 0, stream>>>(c0out, gn0_g, gn0_b, c0out, nullptr);
    conv1_kernel<<<dim3(DD, BB), 256, 0, stream>>>(c0out, convW1, convb1, c1out);
    gn_gelu_kernel<1><<<dim3(DD / 2, BB), 256, 0, stream>>>(c1out, gn1_g, gn1_b, h, hb);

    // ---- transformer ----
    for (int l = 0; l < NL; ++l) {
        const unsigned short* wqkv_l = wqkvb + (size_t)l * QKVS * DD;
        const unsigned short* wo_l   = wob + (size_t)l * DD * DD;
        const unsigned short* w1_l   = w1b + (size_t)l * FFD * DD;
        const unsigned short* w2_l   = w2b + (size_t)l * DD * FFD;

        gemm_mfma<0, 0><<<dim3(QKVS / 128, M / 128), 256, 0, stream>>>(
            hb, wqkv_l, nullptr, bqkv, M, QKVS, DD);
        attn_kernel<<<dim3(SS, NHEAD, BB), 256, 0, stream>>>(bqkv, bab);
        gemm_mfma<0, 0><<<dim3(DD / 128, M / 128), 256, 0, stream>>>(
            bab, wo_l, nullptr, bo, M, DD, DD);
        add_ln_kernel<<<M, 256, 0, stream>>>(
            bo, h, ln1_g + (size_t)l * DD, ln1_b + (size_t)l * DD, hk, hkb);
        gemm_mfma<2, 1><<<dim3(FFD / 128, M / 128), 256, 0, stream>>>(
            hkb, w1_l, b1 + (size_t)l * FFD, ffb, M, FFD, DD);
        gemm_mfma<1, 0><<<dim3(DD / 128, M / 128), 256, 0, stream>>>(
            ffb, w2_l, b2 + (size_t)l * DD, bf2, M, DD, FFD);
        add_ln_kernel<<<M, 256, 0, stream>>>(
            bf2, hk, ln2_g + (size_t)l * DD, ln2_b + (size_t)l * DD, h, hb);
    }

    // ---- deconv decoder ----
    deconv_kernel<<<dim3(CIN, BB), 256, 0, stream>>>(h, Wd, bd, (float*)d_out);
}

// Round 3
// 2103.617 us; speedup vs baseline: 8.1521x; 8.1521x over previous
//
#include <hip/hip_runtime.h>
#include <math.h>

#define BB 16
#define CIN 64
#define TT 1024
#define DD 512
#define SS 512
#define NHEAD 8
#define HD 64
#define FFD 2048
#define NL 8
#define EPSV 1e-5f
#define QKVS 1536

typedef __attribute__((ext_vector_type(8))) short short8v;
typedef __attribute__((ext_vector_type(4))) float f32x4;

// ---------------- helpers ----------------
__device__ __forceinline__ unsigned short f2bf(float f) {
    unsigned u = __float_as_uint(f);
    u = (u + 0x7FFFu + ((u >> 16) & 1u)) >> 16;  // RNE
    return (unsigned short)u;
}

__device__ __forceinline__ void gload_lds16(const void* g, void* l) {
    __builtin_amdgcn_global_load_lds(
        (const __attribute__((address_space(1))) unsigned int*)g,
        (__attribute__((address_space(3))) unsigned int*)l, 16, 0, 0);
}

__device__ __forceinline__ float blk_sum256(float v, float* red) {
    int tid = threadIdx.x;
    red[tid] = v; __syncthreads();
    for (int off = 128; off > 0; off >>= 1) {
        if (tid < off) red[tid] += red[tid + off];
        __syncthreads();
    }
    float r = red[0]; __syncthreads();
    return r;
}

__device__ __forceinline__ float gelu_exact(float x) {
    return 0.5f * x * (1.0f + erff(x * 0.70710678118654752f));
}

// ---------------- fp32 -> bf16 conversions (weights) ----------------
__global__ __launch_bounds__(256) void cvt_bf16_kernel(
        const float* __restrict__ in, unsigned short* __restrict__ out) {
    int i = blockIdx.x * 256 + threadIdx.x;
    float4 v = ((const float4*)in)[i];
    ushort4 o;
    o.x = f2bf(v.x); o.y = f2bf(v.y); o.z = f2bf(v.z); o.w = f2bf(v.w);
    ((ushort4*)out)[i] = o;
}

__global__ __launch_bounds__(256) void cvt_bf16_seg_kernel(
        const float* __restrict__ in, unsigned short* __restrict__ out,
        int seg_elems4, int out_stride4) {
    int i = blockIdx.x * 256 + threadIdx.x;
    int seg = i / seg_elems4, off = i - seg * seg_elems4;
    float4 v = ((const float4*)in)[i];
    ushort4 o;
    o.x = f2bf(v.x); o.y = f2bf(v.y); o.z = f2bf(v.z); o.w = f2bf(v.w);
    ((ushort4*)out)[(size_t)seg * out_stride4 + off] = o;
}

// ---- conv weight reorders (fp32 torch layout -> bf16 GEMM layout) ----
// conv1: W[512 d][512 c][3 k] -> [d][k*512+c]
__global__ __launch_bounds__(256) void reorder_wc1(
        const float* __restrict__ in, unsigned short* __restrict__ out) {
    int i = blockIdx.x * 256 + threadIdx.x;          // 512*1536
    int d = i / 1536, rem = i % 1536;
    int k = rem >> 9, c = rem & 511;
    out[i] = f2bf(in[(size_t)d * 1536 + c * 3 + k]);
}
// conv0: W[512 d][64 c][15 k] -> [d][k*64+c]
__global__ __launch_bounds__(256) void reorder_wc0(
        const float* __restrict__ in, unsigned short* __restrict__ out) {
    int i = blockIdx.x * 256 + threadIdx.x;          // 512*960
    int d = i / 960, rem = i % 960;
    int k = rem >> 6, c = rem & 63;
    out[i] = f2bf(in[(size_t)d * 960 + c * 15 + k]);
}
// deconv: Wd[512 ci][64 co][3 k] -> [128 cols][1024]
// col co (<64, even t): [w[ci][co][1] | 0]; col 64+co (odd t): [w[..][2] | w[..][0]]
__global__ __launch_bounds__(256) void reorder_wdc(
        const float* __restrict__ in, unsigned short* __restrict__ out) {
    int i = blockIdx.x * 256 + threadIdx.x;          // 128*1024
    int col = i >> 10, c = i & 1023;
    int co = col & 63, odd = col >> 6;
    int ci = c & 511, half = c >> 9;
    float v;
    if (!odd) v = half ? 0.f : in[(size_t)ci * 192 + co * 3 + 1];
    else      v = half ? in[(size_t)ci * 192 + co * 3 + 0]
                       : in[(size_t)ci * 192 + co * 3 + 2];
    out[i] = f2bf(v);
}

// ---- transpose+pad: in f32 [B][C][S] -> out bf16 [B][S+2p][C] ----
__global__ __launch_bounds__(256) void transpose_pad(
        const float* __restrict__ in, unsigned short* __restrict__ out,
        int C, int S, int pad) {
    int st = blockIdx.x * 64, ct = blockIdx.y * 64, b = blockIdx.z;
    __shared__ float tile[64][65];
    int tid = threadIdx.x;
    int rr = tid >> 2, cc4 = (tid & 3) * 16;
    const float* ip = in + ((size_t)b * C + ct + rr) * S + st + cc4;
    #pragma unroll
    for (int jj = 0; jj < 4; ++jj) {
        float4 f = *(const float4*)(ip + jj * 4);
        tile[rr][cc4 + jj * 4 + 0] = f.x;
        tile[rr][cc4 + jj * 4 + 1] = f.y;
        tile[rr][cc4 + jj * 4 + 2] = f.z;
        tile[rr][cc4 + jj * 4 + 3] = f.w;
    }
    __syncthreads();
    unsigned short* op = out + ((size_t)b * (S + 2 * pad) + pad + st + rr) * C + ct + cc4;
    #pragma unroll
    for (int jj = 0; jj < 4; ++jj) {
        ushort4 u;
        u.x = f2bf(tile[cc4 + jj * 4 + 0][rr]);
        u.y = f2bf(tile[cc4 + jj * 4 + 1][rr]);
        u.z = f2bf(tile[cc4 + jj * 4 + 2][rr]);
        u.w = f2bf(tile[cc4 + jj * 4 + 3][rr]);
        *(ushort4*)(op + jj * 4) = u;
    }
}

// ---- zero the pad rows (ws is poisoned 0xAA before every launch) ----
__global__ __launch_bounds__(256) void zero_pads(
        unsigned short* __restrict__ xT, unsigned short* __restrict__ c1in,
        unsigned short* __restrict__ hbp) {
    int b = blockIdx.x, tid = threadIdx.x;
    unsigned short* x0 = xT + (size_t)b * 1038 * 64;
    for (int i = tid; i < 448; i += 256) { x0[i] = 0; x0[1031 * 64 + i] = 0; }
    unsigned short* c0 = c1in + (size_t)b * 514 * 512;
    for (int i = tid; i < 512; i += 256) { c0[i] = 0; c0[513 * 512 + i] = 0; }
    unsigned short* h0 = hbp + (size_t)b * 513 * 512 + 512 * 512;
    for (int i = tid; i < 512; i += 256) h0[i] = 0;
}

// ---------------- GroupNorm(2 ch/group) + GELU ----------------
template <int TRANSPOSE>
__global__ __launch_bounds__(256) void gn_gelu_kernel(
        const float* __restrict__ in, const float* __restrict__ g,
        const float* __restrict__ bta, float* __restrict__ out,
        unsigned short* __restrict__ outb) {
    int grp = blockIdx.x, b = blockIdx.y;
    int c0 = grp * 2;
    __shared__ float red[256];
    int tid = threadIdx.x;
    const float* p0 = in + ((size_t)b * DD + c0) * SS;
    float v[4];
    float sum = 0.f;
    #pragma unroll
    for (int j = 0; j < 4; ++j) { v[j] = p0[tid + j * 256]; sum += v[j]; }
    float mean = blk_sum256(sum, red) * (1.0f / 1024.0f);
    float vs = 0.f;
    #pragma unroll
    for (int j = 0; j < 4; ++j) { float dlt = v[j] - mean; vs += dlt * dlt; }
    float var = blk_sum256(vs, red) * (1.0f / 1024.0f);
    float rs = rsqrtf(var + EPSV);
    #pragma unroll
    for (int j = 0; j < 4; ++j) {
        int f = tid + j * 256;
        int cl = f >> 9;
        int s = f & 511;
        float xn = (v[j] - mean) * rs * g[c0 + cl] + bta[c0 + cl];
        float ge = gelu_exact(xn);
        if (TRANSPOSE) {
            out[((size_t)b * SS + s) * DD + (c0 + cl)] = ge;           // h fp32 [B,S,D]
            outb[((size_t)b * 513 + s) * DD + (c0 + cl)] = f2bf(ge);   // hb bf16 padded
        } else {
            out[((size_t)b * DD + c0) * SS + f] = ge;                  // fp32 [B,D,S]
        }
    }
}

// ---------------- MFMA GEMM: C[M,N] = A @ W[N,K]^T ----------------
// Generalized A addressing: row m starts at elem m*rp + (m>>9)*bp (bf16).
// STORE: 0 f32 [M][N] | 1 bf16 [M][N] | 2 f32 [B][N][512] (conv, transposed)
//        3 QKV: bf16 [M][1536] for col<1024, V -> vT[b*8+h][d][512] ushort4
//        4 deconv scatter: f32 out[b][co][1024], t=2*s+odd
// EPI: 0 none, 1 +bias, 2 +bias+relu (bias idx col, STORE4: col&63)
template <int EPI, int STORE>
__global__ __launch_bounds__(256) void gemm_mfma(
        const unsigned short* __restrict__ A, const unsigned short* __restrict__ W,
        const float* __restrict__ bias, void* __restrict__ Cout,
        unsigned short* __restrict__ vT,
        int M, int N, int K, int rp, int bp) {
    __shared__ char smem[32768];
    char* sA = smem;
    char* sB = smem + 16384;
    int tid = threadIdx.x;
    int bn = blockIdx.x * 128, bm = blockIdx.y * 128;
    int lane = tid & 63, wid = tid >> 6;
    int wm = wid >> 1, wn = wid & 1;
    int r = lane & 15, g = lane >> 4;
    f32x4 acc[4][4] = {};

    int srow = tid >> 3;
    int u = tid & 7;

    for (int kk = 0; kk < K; kk += 64) {
        #pragma unroll
        for (int i = 0; i < 4; ++i) {
            int row = i * 32 + srow;
            int u0 = u ^ (row & 7);
            int mrow = bm + row;
            const char* ga = (const char*)(A + (size_t)mrow * rp + (size_t)(mrow >> 9) * bp + kk) + u0 * 16;
            gload_lds16(ga, sA + row * 128 + u * 16);
            const char* gb = (const char*)(W + (size_t)(bn + row) * K + kk) + u0 * 16;
            gload_lds16(gb, sB + row * 128 + u * 16);
        }
        __syncthreads();
        #pragma unroll
        for (int ks = 0; ks < 2; ++ks) {
            short8v af[4], bf[4];
            #pragma unroll
            for (int i = 0; i < 4; ++i) {
                int rowA = wm * 64 + i * 16 + r;
                af[i] = *(const short8v*)(sA + rowA * 128 + (((ks * 4 + g) ^ (rowA & 7)) * 16));
                int rowB = wn * 64 + i * 16 + r;
                bf[i] = *(const short8v*)(sB + rowB * 128 + (((ks * 4 + g) ^ (rowB & 7)) * 16));
            }
            #pragma unroll
            for (int i = 0; i < 4; ++i)
                #pragma unroll
                for (int j = 0; j < 4; ++j)
                    acc[i][j] = __builtin_amdgcn_mfma_f32_16x16x32_bf16(
                        af[i], bf[j], acc[i][j], 0, 0, 0);
        }
        __syncthreads();
    }

    float* Cf = (float*)Cout;
    unsigned short* Cb = (unsigned short*)Cout;
    #pragma unroll
    for (int i = 0; i < 4; ++i) {
        int row0 = bm + wm * 64 + i * 16 + g * 4;
        #pragma unroll
        for (int j = 0; j < 4; ++j) {
            int col = bn + wn * 64 + j * 16 + r;
            float bval = (EPI >= 1) ? bias[STORE == 4 ? (col & 63) : col] : 0.f;
            float v[4];
            #pragma unroll
            for (int e = 0; e < 4; ++e) {
                float t = acc[i][j][e] + bval;
                v[e] = (EPI == 2) ? fmaxf(t, 0.f) : t;
            }
            if (STORE == 0) {
                #pragma unroll
                for (int e = 0; e < 4; ++e) Cf[(size_t)(row0 + e) * N + col] = v[e];
            } else if (STORE == 1) {
                #pragma unroll
                for (int e = 0; e < 4; ++e) Cb[(size_t)(row0 + e) * N + col] = f2bf(v[e]);
            } else if (STORE == 2) {
                float4 f4 = {v[0], v[1], v[2], v[3]};
                *(float4*)(Cf + ((size_t)(row0 >> 9) * N + col) * 512 + (row0 & 511)) = f4;
            } else if (STORE == 3) {
                if (col < 1024) {
                    #pragma unroll
                    for (int e = 0; e < 4; ++e) Cb[(size_t)(row0 + e) * N + col] = f2bf(v[e]);
                } else {
                    ushort4 u4;
                    u4.x = f2bf(v[0]); u4.y = f2bf(v[1]); u4.z = f2bf(v[2]); u4.w = f2bf(v[3]);
                    int hh = (col - 1024) >> 6, dd = (col - 1024) & 63;
                    *(ushort4*)(vT + ((size_t)((row0 >> 9) * 8 + hh) * 64 + dd) * 512 + (row0 & 511)) = u4;
                }
            } else {  // STORE == 4
                int b = row0 >> 9, s0 = row0 & 511;
                int co = col & 63, odd = col >> 6;
                float* outp = Cf + (size_t)b * 65536 + (size_t)co * 1024 + 2 * s0 + odd;
                #pragma unroll
                for (int e = 0; e < 4; ++e) outp[2 * e] = v[e];
            }
        }
    }
}

// ---------------- MFMA attention ----------------
// QKV bf16 [8192][1536] (q+0,k+512), vT bf16 [b*8+h][64][512], O bf16 [8192][512]
// Block: (qblock 8, head 8, batch 16), 4 waves, 16 q-rows/wave, full S=512 softmax.
__global__ __launch_bounds__(256) void attn_mfma(
        const unsigned short* __restrict__ QKV,
        const unsigned short* __restrict__ vT,
        unsigned short* __restrict__ O) {
    __shared__ char psm[65536];          // 16KB per wave: P[16 q][512 k] bf16, swizzled
    int tid = threadIdx.x;
    int lane = tid & 63, wid = tid >> 6;
    int qb = blockIdx.x, hh = blockIdx.y, b = blockIdx.z;
    int r = lane & 15, g = lane >> 4;
    int q0 = g * 4;
    int qbase = qb * 64 + wid * 16;
    size_t browbase = (size_t)b * SS;

    // Q A-fragments (2 d-chunks of 32)
    const char* qptr = (const char*)(QKV + (browbase + qbase + r) * QKVS + hh * 64);
    short8v aq0 = *(const short8v*)(qptr + g * 16);
    short8v aq1 = *(const short8v*)(qptr + 64 + g * 16);

    // QK^T: 32 k-tiles of 16 -> lane holds S[q0+e][kt*16+r]
    const char* kbase = (const char*)(QKV + browbase * QKVS + 512 + hh * 64);
    f32x4 sc[32];
    #pragma unroll
    for (int t = 0; t < 32; ++t) {
        const char* kr = kbase + (size_t)(t * 16 + r) * 3072;
        short8v bk0 = *(const short8v*)(kr + g * 16);
        short8v bk1 = *(const short8v*)(kr + 64 + g * 16);
        f32x4 z = {0.f, 0.f, 0.f, 0.f};
        z = __builtin_amdgcn_mfma_f32_16x16x32_bf16(aq0, bk0, z, 0, 0, 0);
        z = __builtin_amdgcn_mfma_f32_16x16x32_bf16(aq1, bk1, z, 0, 0, 0);
        sc[t] = z;
    }
    // row max (raw scores; 1/8 scale folded into exp)
    float mx[4] = {-1e30f, -1e30f, -1e30f, -1e30f};
    #pragma unroll
    for (int t = 0; t < 32; ++t)
        #pragma unroll
        for (int e = 0; e < 4; ++e) mx[e] = fmaxf(mx[e], sc[t][e]);
    #pragma unroll
    for (int m = 1; m < 16; m <<= 1)
        #pragma unroll
        for (int e = 0; e < 4; ++e) mx[e] = fmaxf(mx[e], __shfl_xor(mx[e], m, 64));
    // exp, sum, write P (bf16) to LDS [q][512] with 16B-slot XOR swizzle
    float sm[4] = {0.f, 0.f, 0.f, 0.f};
    char* pb = psm + wid * 16384;
    #pragma unroll
    for (int t = 0; t < 32; ++t) {
        int k = t * 16 + r;
        int slot = k >> 3;
        int koff = (k & 7) * 2;
        #pragma unroll
        for (int e = 0; e < 4; ++e) {
            float p = __expf((sc[t][e] - mx[e]) * 0.125f);
            sm[e] += p;
            int q = q0 + e;
            *(unsigned short*)(pb + q * 1024 + ((slot ^ (q & 7)) << 4) + koff) = f2bf(p);
        }
    }
    #pragma unroll
    for (int m = 1; m < 16; m <<= 1)
        #pragma unroll
        for (int e = 0; e < 4; ++e) sm[e] += __shfl_xor(sm[e], m, 64);
    __syncthreads();
    // PV: O[16q][64d] += P[16q,32k] * V[32k,16d]
    f32x4 o[4] = {};
    const char* vb = (const char*)(vT + ((size_t)(b * 8 + hh) * 64) * 512);
    #pragma unroll
    for (int kc = 0; kc < 16; ++kc) {
        short8v pa = *(const short8v*)(pb + r * 1024 + (((kc * 4 + g) ^ (r & 7)) << 4));
        #pragma unroll
        for (int dt = 0; dt < 4; ++dt) {
            short8v bv = *(const short8v*)(vb + (size_t)(dt * 16 + r) * 1024 + kc * 64 + g * 16);
            o[dt] = __builtin_amdgcn_mfma_f32_16x16x32_bf16(pa, bv, o[dt], 0, 0, 0);
        }
    }
    float inv[4];
    #pragma unroll
    for (int e = 0; e < 4; ++e) inv[e] = 1.0f / sm[e];
    unsigned short* ob = O + (browbase + qbase) * 512 + hh * 64;
    #pragma unroll
    for (int dt = 0; dt < 4; ++dt)
        #pragma unroll
        for (int e = 0; e < 4; ++e)
            ob[(size_t)(q0 + e) * 512 + dt * 16 + r] = f2bf(o[dt][e] * inv[e]);
}

// ---------------- fused add + LayerNorm ----------------
// PADB=1: outb uses padded residual layout [B][513][512]
template <int PADB>
__global__ __launch_bounds__(256) void add_ln_kernel(
        const float* __restrict__ A, const float* __restrict__ R,
        const float* __restrict__ g, const float* __restrict__ bta,
        float* __restrict__ out, unsigned short* __restrict__ outb) {
    int row = blockIdx.x;
    int tid = threadIdx.x;
    __shared__ float red[256];
    const float* a = A + (size_t)row * DD;
    const float* r = R + (size_t)row * DD;
    float x0 = a[tid] + r[tid];
    float x1 = a[tid + 256] + r[tid + 256];
    float mean = blk_sum256(x0 + x1, red) * (1.0f / DD);
    float d0 = x0 - mean, d1 = x1 - mean;
    float var = blk_sum256(d0 * d0 + d1 * d1, red) * (1.0f / DD);
    float rs = rsqrtf(var + EPSV);
    float y0 = d0 * rs * g[tid] + bta[tid];
    float y1 = d1 * rs * g[tid + 256] + bta[tid + 256];
    size_t o0 = (size_t)row * DD + tid;
    out[o0] = y0; out[o0 + 256] = y1;
    size_t ob = PADB ? ((size_t)row + (row >> 9)) * DD + tid : o0;
    outb[ob] = f2bf(y0); outb[ob + 256] = f2bf(y1);
}

// ---------------- host launch ----------------
extern "C" void kernel_launch(void* const* d_in, const int* in_sizes, int n_in,
                              void* d_out, int out_size, void* d_ws, size_t ws_size,
                              hipStream_t stream) {
    const float* x      = (const float*)d_in[0];
    const float* convW0 = (const float*)d_in[1];
    const float* convb0 = (const float*)d_in[2];
    const float* gn0_g  = (const float*)d_in[3];
    const float* gn0_b  = (const float*)d_in[4];
    const float* convW1 = (const float*)d_in[5];
    const float* convb1 = (const float*)d_in[6];
    const float* gn1_g  = (const float*)d_in[7];
    const float* gn1_b  = (const float*)d_in[8];
    const float* Wq     = (const float*)d_in[9];
    const float* Wk     = (const float*)d_in[10];
    const float* Wv     = (const float*)d_in[11];
    const float* Wo     = (const float*)d_in[12];
    const float* W1     = (const float*)d_in[13];
    const float* b1     = (const float*)d_in[14];
    const float* W2     = (const float*)d_in[15];
    const float* b2     = (const float*)d_in[16];
    const float* ln1_g  = (const float*)d_in[17];
    const float* ln1_b  = (const float*)d_in[18];
    const float* ln2_g  = (const float*)d_in[19];
    const float* ln2_b  = (const float*)d_in[20];
    const float* Wd     = (const float*)d_in[21];
    const float* bd     = (const float*)d_in[22];

    const int M = BB * SS;                       // 8192
    const size_t NBUF = (size_t)M * DD;          // 4,194,304

    // ---- workspace layout ----
    char* p = (char*)d_ws;
    auto alloc = [&](size_t bytes) { char* q = p; p += (bytes + 255) & ~(size_t)255; return q; };
    float* h   = (float*)alloc(NBUF * 4);                     // residual fp32 [M][512]
    float* hk  = (float*)alloc(NBUF * 4);                     // post-LN1 fp32
    float* bo  = (float*)alloc(NBUF * 4);                     // O-proj / FF2 out fp32
    float* bf2 = bo;
    char* S1 = alloc((size_t)M * FFD * 2);                    // 32MB shared region
    unsigned short* bqkv16 = (unsigned short*)S1;             // [M][1536] bf16
    unsigned short* vTb    = (unsigned short*)(S1 + (size_t)M * QKVS * 2);  // [128][64][512]
    unsigned short* ffb    = (unsigned short*)S1;             // [M][2048] bf16 (after attn)
    unsigned short* hb  = (unsigned short*)alloc((size_t)BB * 513 * 512 * 2);  // padded residual bf16
    unsigned short* hkb = (unsigned short*)alloc(NBUF * 2);   // also bab (disjoint lifetimes)
    unsigned short* bab = hkb;
    unsigned short* xT  = (unsigned short*)alloc((size_t)BB * 1038 * 64 * 2);
    unsigned short* c1in = (unsigned short*)alloc((size_t)BB * 514 * 512 * 2);
    float* c0out = (float*)alloc(NBUF * 4);                   // conv0/conv1 out fp32 [B][D][S]
    float* c1out = c0out;
    unsigned short* wqkvb = (unsigned short*)alloc((size_t)NL * QKVS * DD * 2);
    unsigned short* wob   = (unsigned short*)alloc((size_t)NL * DD * DD * 2);
    unsigned short* w1b   = (unsigned short*)alloc((size_t)NL * FFD * DD * 2);
    unsigned short* w2b   = (unsigned short*)alloc((size_t)NL * DD * FFD * 2);
    unsigned short* wc1   = (unsigned short*)alloc((size_t)DD * 1536 * 2);
    unsigned short* wc0   = (unsigned short*)alloc((size_t)DD * 960 * 2);
    unsigned short* wdc   = (unsigned short*)alloc((size_t)128 * 1024 * 2);

    // ---- weight prep ----
    {
        int seg4 = DD * DD / 4, ostr4 = QKVS * DD / 4;
        int blks = NL * seg4 / 256;
        cvt_bf16_seg_kernel<<<blks, 256, 0, stream>>>(Wq, wqkvb, seg4, ostr4);
        cvt_bf16_seg_kernel<<<blks, 256, 0, stream>>>(Wk, wqkvb + (size_t)DD * DD, seg4, ostr4);
        cvt_bf16_seg_kernel<<<blks, 256, 0, stream>>>(Wv, wqkvb + (size_t)2 * DD * DD, seg4, ostr4);
        cvt_bf16_kernel<<<NL * DD * DD / 1024, 256, 0, stream>>>(Wo, wob);
        cvt_bf16_kernel<<<NL * FFD * DD / 1024, 256, 0, stream>>>(W1, w1b);
        cvt_bf16_kernel<<<NL * DD * FFD / 1024, 256, 0, stream>>>(W2, w2b);
        reorder_wc1<<<DD * 1536 / 256, 256, 0, stream>>>(convW1, wc1);
        reorder_wc0<<<DD * 960 / 256, 256, 0, stream>>>(convW0, wc0);
        reorder_wdc<<<128 * 1024 / 256, 256, 0, stream>>>(Wd, wdc);
        zero_pads<<<BB, 256, 0, stream>>>(xT, c1in, hb);
    }

    // ---- conv encoder ----
    transpose_pad<<<dim3(TT / 64, 1, BB), 256, 0, stream>>>(x, xT, CIN, TT, 7);
    gemm_mfma<1, 2><<<dim3(4, 64), 256, 0, stream>>>(
        xT, wc0, convb0, c0out, nullptr, M, DD, 960, 128, 896);
    gn_gelu_kernel<0><<<dim3(DD / 2, BB), 256, 0, stream>>>(c0out, gn0_g, gn0_b, c0out, nullptr);
    transpose_pad<<<dim3(SS / 64, DD / 64, BB), 256, 0, stream>>>(c0out, c1in, DD, SS, 1);
    gemm_mfma<1, 2><<<dim3(4, 64), 256, 0, stream>>>(
        c1in, wc1, convb1, c1out, nullptr, M, DD, 1536, 512, 1024);
    gn_gelu_kernel<1><<<dim3(DD / 2, BB), 256, 0, stream>>>(c1out, gn1_g, gn1_b, h, hb);

    // ---- transformer ----
    for (int l = 0; l < NL; ++l) {
        const unsigned short* wqkv_l = wqkvb + (size_t)l * QKVS * DD;
        const unsigned short* wo_l   = wob + (size_t)l * DD * DD;
        const unsigned short* w1_l   = w1b + (size_t)l * FFD * DD;
        const unsigned short* w2_l   = w2b + (size_t)l * DD * FFD;

        gemm_mfma<0, 3><<<dim3(QKVS / 128, 64), 256, 0, stream>>>(
            hb, wqkv_l, nullptr, bqkv16, vTb, M, QKVS, DD, 512, 512);
        attn_mfma<<<dim3(8, NHEAD, BB), 256, 0, stream>>>(bqkv16, vTb, bab);
        gemm_mfma<0, 0><<<dim3(4, 64), 256, 0, stream>>>(
            bab, wo_l, nullptr, bo, nullptr, M, DD, DD, 512, 0);
        add_ln_kernel<0><<<M, 256, 0, stream>>>(
            bo, h, ln1_g + (size_t)l * DD, ln1_b + (size_t)l * DD, hk, hkb);
        gemm_mfma<2, 1><<<dim3(FFD / 128, 64), 256, 0, stream>>>(
            hkb, w1_l, b1 + (size_t)l * FFD, ffb, nullptr, M, FFD, DD, 512, 0);
        gemm_mfma<1, 0><<<dim3(4, 64), 256, 0, stream>>>(
            ffb, w2_l, b2 + (size_t)l * DD, bf2, nullptr, M, DD, FFD, 2048, 0);
        add_ln_kernel<1><<<M, 256, 0, stream>>>(
            bf2, hk, ln2_g + (size_t)l * DD, ln2_b + (size_t)l * DD, h, hb);
    }

    // ---- deconv decoder (one GEMM, scatter store) ----
    gemm_mfma<1, 4><<<dim3(1, 64), 256, 0, stream>>>(
        hb, wdc, bd, (float*)d_out, nullptr, M, 128, 1024, 512, 512);
}

// Round 10
// 1417.889 us; speedup vs baseline: 12.0947x; 1.4836x over previous
//
#include <hip/hip_runtime.h>
#include <math.h>

#define BB 16
#define CIN 64
#define TT 1024
#define DD 512
#define SS 512
#define NHEAD 8
#define HD 64
#define FFD 2048
#define NL 8
#define EPSV 1e-5f
#define QKVS 1536

typedef __attribute__((ext_vector_type(8))) short short8v;
typedef __attribute__((ext_vector_type(4))) float f32x4;

// ---------------- helpers ----------------
__device__ __forceinline__ unsigned short f2bf(float f) {
    unsigned u = __float_as_uint(f);
    u = (u + 0x7FFFu + ((u >> 16) & 1u)) >> 16;  // RNE
    return (unsigned short)u;
}

__device__ __forceinline__ void gload_lds16(const void* g, void* l) {
    __builtin_amdgcn_global_load_lds(
        (const __attribute__((address_space(1))) unsigned int*)g,
        (__attribute__((address_space(3))) unsigned int*)l, 16, 0, 0);
}

__device__ __forceinline__ float gelu_exact(float x) {
    return 0.5f * x * (1.0f + erff(x * 0.70710678118654752f));
}

// ---------------- fp32 -> bf16 conversions (weights) ----------------
__global__ __launch_bounds__(256) void cvt_bf16_kernel(
        const float* __restrict__ in, unsigned short* __restrict__ out) {
    int i = blockIdx.x * 256 + threadIdx.x;
    float4 v = ((const float4*)in)[i];
    ushort4 o;
    o.x = f2bf(v.x); o.y = f2bf(v.y); o.z = f2bf(v.z); o.w = f2bf(v.w);
    ((ushort4*)out)[i] = o;
}

__global__ __launch_bounds__(256) void cvt_bf16_seg_kernel(
        const float* __restrict__ in, unsigned short* __restrict__ out,
        int seg_elems4, int out_stride4) {
    int i = blockIdx.x * 256 + threadIdx.x;
    int seg = i / seg_elems4, off = i - seg * seg_elems4;
    float4 v = ((const float4*)in)[i];
    ushort4 o;
    o.x = f2bf(v.x); o.y = f2bf(v.y); o.z = f2bf(v.z); o.w = f2bf(v.w);
    ((ushort4*)out)[(size_t)seg * out_stride4 + off] = o;
}

// ---- conv weight reorders ----
__global__ __launch_bounds__(256) void reorder_wc1(
        const float* __restrict__ in, unsigned short* __restrict__ out) {
    int i = blockIdx.x * 256 + threadIdx.x;          // 512*1536
    int d = i / 1536, rem = i % 1536;
    int k = rem >> 9, c = rem & 511;
    out[i] = f2bf(in[(size_t)d * 1536 + c * 3 + k]);
}
__global__ __launch_bounds__(256) void reorder_wc0(
        const float* __restrict__ in, unsigned short* __restrict__ out) {
    int i = blockIdx.x * 256 + threadIdx.x;          // 512*960
    int d = i / 960, rem = i % 960;
    int k = rem >> 6, c = rem & 63;
    out[i] = f2bf(in[(size_t)d * 960 + c * 15 + k]);
}
__global__ __launch_bounds__(256) void reorder_wdc(
        const float* __restrict__ in, unsigned short* __restrict__ out) {
    int i = blockIdx.x * 256 + threadIdx.x;          // 128*1024
    int col = i >> 10, c = i & 1023;
    int co = col & 63, odd = col >> 6;
    int ci = c & 511, half = c >> 9;
    float v;
    if (!odd) v = half ? 0.f : in[(size_t)ci * 192 + co * 3 + 1];
    else      v = half ? in[(size_t)ci * 192 + co * 3 + 0]
                       : in[(size_t)ci * 192 + co * 3 + 2];
    out[i] = f2bf(v);
}

// ---- transpose+pad: in f32 [B][C][S] -> out bf16 [B][S+2p][C] ----
__global__ __launch_bounds__(256) void transpose_pad(
        const float* __restrict__ in, unsigned short* __restrict__ out,
        int C, int S, int pad) {
    int st = blockIdx.x * 64, ct = blockIdx.y * 64, b = blockIdx.z;
    __shared__ float tile[64][65];
    int tid = threadIdx.x;
    int rr = tid >> 2, cc4 = (tid & 3) * 16;
    const float* ip = in + ((size_t)b * C + ct + rr) * S + st + cc4;
    #pragma unroll
    for (int jj = 0; jj < 4; ++jj) {
        float4 f = *(const float4*)(ip + jj * 4);
        tile[rr][cc4 + jj * 4 + 0] = f.x;
        tile[rr][cc4 + jj * 4 + 1] = f.y;
        tile[rr][cc4 + jj * 4 + 2] = f.z;
        tile[rr][cc4 + jj * 4 + 3] = f.w;
    }
    __syncthreads();
    unsigned short* op = out + ((size_t)b * (S + 2 * pad) + pad + st + rr) * C + ct + cc4;
    #pragma unroll
    for (int jj = 0; jj < 4; ++jj) {
        ushort4 u;
        u.x = f2bf(tile[cc4 + jj * 4 + 0][rr]);
        u.y = f2bf(tile[cc4 + jj * 4 + 1][rr]);
        u.z = f2bf(tile[cc4 + jj * 4 + 2][rr]);
        u.w = f2bf(tile[cc4 + jj * 4 + 3][rr]);
        *(ushort4*)(op + jj * 4) = u;
    }
}

// ---- zero the pad rows ----
__global__ __launch_bounds__(256) void zero_pads(
        unsigned short* __restrict__ xT, unsigned short* __restrict__ c1in,
        unsigned short* __restrict__ hbp) {
    int b = blockIdx.x, tid = threadIdx.x;
    unsigned short* x0 = xT + (size_t)b * 1038 * 64;
    for (int i = tid; i < 448; i += 256) { x0[i] = 0; x0[1031 * 64 + i] = 0; }
    unsigned short* c0 = c1in + (size_t)b * 514 * 512;
    for (int i = tid; i < 512; i += 256) { c0[i] = 0; c0[513 * 512 + i] = 0; }
    unsigned short* h0 = hbp + (size_t)b * 513 * 512 + 512 * 512;
    for (int i = tid; i < 512; i += 256) h0[i] = 0;
}

// ---------------- GroupNorm stats: one wave per group (2ch = 1024 floats) ----
__global__ __launch_bounds__(256) void gn_stats_kernel(
        const float* __restrict__ in, float2* __restrict__ stats) {
    int grp = blockIdx.x * 4 + (threadIdx.x >> 6);   // over B*256
    int lane = threadIdx.x & 63;
    const float4* p = (const float4*)(in + (size_t)grp * 1024);
    float4 v[4];
    float sum = 0.f;
    #pragma unroll
    for (int i = 0; i < 4; ++i) {
        v[i] = p[lane + 64 * i];
        sum += v[i].x + v[i].y + v[i].z + v[i].w;
    }
    #pragma unroll
    for (int mm = 1; mm < 64; mm <<= 1) sum += __shfl_xor(sum, mm, 64);
    float mean = sum * (1.f / 1024.f);
    float vs = 0.f;
    #pragma unroll
    for (int i = 0; i < 4; ++i) {
        float a = v[i].x - mean, b = v[i].y - mean, c = v[i].z - mean, d = v[i].w - mean;
        vs += a * a + b * b + c * c + d * d;
    }
    #pragma unroll
    for (int mm = 1; mm < 64; mm <<= 1) vs += __shfl_xor(vs, mm, 64);
    if (lane == 0) {
        float2 st;
        st.x = mean;
        st.y = rsqrtf(vs * (1.f / 1024.f) + EPSV);
        stats[grp] = st;
    }
}

// ---------------- GroupNorm apply + GELU + transpose (coalesced writes) ----
// in f32 [B][512 c][512 s]. F32OUT=1: also write outf f32 [B][s][c].
// outb bf16 [B][spad][512] rows offset by `pad`.
template <int F32OUT>
__global__ __launch_bounds__(256) void gn_apply_kernel(
        const float* __restrict__ in, const float2* __restrict__ stats,
        const float* __restrict__ gamma, const float* __restrict__ beta,
        float* __restrict__ outf, unsigned short* __restrict__ outb,
        int spad, int pad) {
    int st = blockIdx.x * 64, ct = blockIdx.y * 64, b = blockIdx.z;
    __shared__ float tile[64][65];
    int tid = threadIdx.x;
    int rr = tid >> 2, cc4 = (tid & 3) * 16;
    int c = ct + rr;
    float2 ms = stats[b * 256 + (c >> 1)];
    float ga = gamma[c] * ms.y;
    float bt = beta[c] - ms.x * ga;
    const float* ip = in + ((size_t)b * DD + c) * SS + st + cc4;
    #pragma unroll
    for (int jj = 0; jj < 4; ++jj) {
        float4 f = *(const float4*)(ip + jj * 4);
        tile[rr][cc4 + jj * 4 + 0] = gelu_exact(f.x * ga + bt);
        tile[rr][cc4 + jj * 4 + 1] = gelu_exact(f.y * ga + bt);
        tile[rr][cc4 + jj * 4 + 2] = gelu_exact(f.z * ga + bt);
        tile[rr][cc4 + jj * 4 + 3] = gelu_exact(f.w * ga + bt);
    }
    __syncthreads();
    // write rows s = st+rr, cols ct..ct+63
    if (F32OUT) {
        float* op = outf + ((size_t)b * SS + st + rr) * DD + ct + cc4;
        #pragma unroll
        for (int jj = 0; jj < 4; ++jj) {
            float4 f;
            f.x = tile[cc4 + jj * 4 + 0][rr];
            f.y = tile[cc4 + jj * 4 + 1][rr];
            f.z = tile[cc4 + jj * 4 + 2][rr];
            f.w = tile[cc4 + jj * 4 + 3][rr];
            *(float4*)(op + jj * 4) = f;
        }
    }
    unsigned short* obp = outb + ((size_t)b * spad + pad + st + rr) * DD + ct + cc4;
    #pragma unroll
    for (int jj = 0; jj < 4; ++jj) {
        ushort4 u;
        u.x = f2bf(tile[cc4 + jj * 4 + 0][rr]);
        u.y = f2bf(tile[cc4 + jj * 4 + 1][rr]);
        u.z = f2bf(tile[cc4 + jj * 4 + 2][rr]);
        u.w = f2bf(tile[cc4 + jj * 4 + 3][rr]);
        *(ushort4*)(obp + jj * 4) = u;
    }
}

// ---------------- MFMA GEMM: C[M,N] = A @ W[N,K]^T ----------------
// DBUF=1: LDS double-buffer, raw barriers + counted vmcnt (loads stay in
// flight across barriers) — for 1-block/CU grids where no inter-block
// latency hiding exists. DBUF=0: classic 2-barrier loop (3-4 blocks/CU).
template <int EPI, int STORE, int DBUF>
__global__ __launch_bounds__(256) void gemm_mfma(
        const unsigned short* __restrict__ A, const unsigned short* __restrict__ W,
        const float* __restrict__ bias, void* __restrict__ Cout,
        unsigned short* __restrict__ vT,
        int M, int N, int K, int rp, int bp) {
    __shared__ char smem[DBUF ? 65536 : 32768];
    int tid = threadIdx.x;
    int bn = blockIdx.x * 128, bm = blockIdx.y * 128;
    int lane = tid & 63, wid = tid >> 6;
    int wm = wid >> 1, wn = wid & 1;
    int r = lane & 15, g = lane >> 4;
    f32x4 acc[4][4] = {};
    int srow = tid >> 3;
    int u = tid & 7;

    auto STAGE = [&](int buf, int kk) {
        char* sA = smem + buf * 32768;
        char* sB = sA + 16384;
        #pragma unroll
        for (int i = 0; i < 4; ++i) {
            int row = i * 32 + srow;
            int u0 = u ^ (row & 7);
            int mrow = bm + row;
            gload_lds16((const char*)(A + (size_t)mrow * rp + (size_t)(mrow >> 9) * bp + kk) + u0 * 16,
                        sA + row * 128 + u * 16);
            gload_lds16((const char*)(W + (size_t)(bn + row) * K + kk) + u0 * 16,
                        sB + row * 128 + u * 16);
        }
    };
    auto COMPUTE = [&](int buf) {
        char* sA = smem + buf * 32768;
        char* sB = sA + 16384;
        #pragma unroll
        for (int ks = 0; ks < 2; ++ks) {
            short8v af[4], bf[4];
            #pragma unroll
            for (int i = 0; i < 4; ++i) {
                int rowA = wm * 64 + i * 16 + r;
                af[i] = *(const short8v*)(sA + rowA * 128 + (((ks * 4 + g) ^ (rowA & 7)) * 16));
                int rowB = wn * 64 + i * 16 + r;
                bf[i] = *(const short8v*)(sB + rowB * 128 + (((ks * 4 + g) ^ (rowB & 7)) * 16));
            }
            #pragma unroll
            for (int i = 0; i < 4; ++i)
                #pragma unroll
                for (int j = 0; j < 4; ++j)
                    acc[i][j] = __builtin_amdgcn_mfma_f32_16x16x32_bf16(
                        af[i], bf[j], acc[i][j], 0, 0, 0);
        }
    };

    if (DBUF) {
        const int NT = K >> 6;
        STAGE(0, 0);
        for (int t = 0; t < NT; ++t) {
            int cur = t & 1;
            __builtin_amdgcn_s_barrier();           // all waves done reading buf[cur^1]
            if (t + 1 < NT) {
                STAGE(cur ^ 1, (t + 1) << 6);
                asm volatile("s_waitcnt vmcnt(8)" ::: "memory");  // tile t landed; t+1 in flight
            } else {
                asm volatile("s_waitcnt vmcnt(0)" ::: "memory");
            }
            __builtin_amdgcn_s_barrier();           // buf[cur] ready for everyone
            COMPUTE(cur);
        }
    } else {
        for (int kk = 0; kk < K; kk += 64) {
            STAGE(0, kk);
            __syncthreads();
            COMPUTE(0);
            __syncthreads();
        }
    }

    float* Cf = (float*)Cout;
    unsigned short* Cb = (unsigned short*)Cout;
    #pragma unroll
    for (int i = 0; i < 4; ++i) {
        int row0 = bm + wm * 64 + i * 16 + g * 4;
        #pragma unroll
        for (int j = 0; j < 4; ++j) {
            int col = bn + wn * 64 + j * 16 + r;
            float bval = (EPI >= 1) ? bias[STORE == 4 ? (col & 63) : col] : 0.f;
            float v[4];
            #pragma unroll
            for (int e = 0; e < 4; ++e) {
                float t = acc[i][j][e] + bval;
                v[e] = (EPI == 2) ? fmaxf(t, 0.f) : t;
            }
            if (STORE == 0) {
                #pragma unroll
                for (int e = 0; e < 4; ++e) Cf[(size_t)(row0 + e) * N + col] = v[e];
            } else if (STORE == 1) {
                #pragma unroll
                for (int e = 0; e < 4; ++e) Cb[(size_t)(row0 + e) * N + col] = f2bf(v[e]);
            } else if (STORE == 2) {
                float4 f4 = {v[0], v[1], v[2], v[3]};
                *(float4*)(Cf + ((size_t)(row0 >> 9) * N + col) * 512 + (row0 & 511)) = f4;
            } else if (STORE == 3) {
                if (col < 1024) {
                    #pragma unroll
                    for (int e = 0; e < 4; ++e) Cb[(size_t)(row0 + e) * N + col] = f2bf(v[e]);
                } else {
                    ushort4 u4;
                    u4.x = f2bf(v[0]); u4.y = f2bf(v[1]); u4.z = f2bf(v[2]); u4.w = f2bf(v[3]);
                    int hh = (col - 1024) >> 6, dd = (col - 1024) & 63;
                    *(ushort4*)(vT + ((size_t)((row0 >> 9) * 8 + hh) * 64 + dd) * 512 + (row0 & 511)) = u4;
                }
            } else {  // STORE == 4
                int b = row0 >> 9, s0 = row0 & 511;
                int co = col & 63, odd = col >> 6;
                float* outp = Cf + (size_t)b * 65536 + (size_t)co * 1024 + 2 * s0 + odd;
                #pragma unroll
                for (int e = 0; e < 4; ++e) outp[2 * e] = v[e];
            }
        }
    }
}

// ---------------- flash attention (MFMA, LDS-staged K/V, online softmax) ----
// QKV bf16 [8192][1536] (q+0,k+512), vT bf16 [b*8+h][64 d][512 s], O bf16 [8192][512]
// block = 64 q rows (4 waves x 16), loops over 4 k-tiles of 128.
__global__ __launch_bounds__(256) void attn_flash(
        const unsigned short* __restrict__ QKV,
        const unsigned short* __restrict__ vT,
        unsigned short* __restrict__ O) {
    __shared__ char sK[16384];   // [128 k][64 d] bf16, 8 slots/row, slot^(row&7)
    __shared__ char sV[16384];   // [64 d][128 k] bf16, 16 slots/row, slot^((d&7)<<1)
    __shared__ char sP[16384];   // 4 waves x [16 q][128 k] bf16
    int tid = threadIdx.x;
    int lane = tid & 63, wid = tid >> 6;
    int qb = blockIdx.x, hh = blockIdx.y, b = blockIdx.z;
    int r = lane & 15, g = lane >> 4;
    int qbase = qb * 64 + wid * 16;
    size_t browbase = (size_t)b * SS;

    const char* qptr = (const char*)(QKV + (browbase + qbase + r) * QKVS + hh * 64);
    short8v aq0 = *(const short8v*)(qptr + g * 16);
    short8v aq1 = *(const short8v*)(qptr + 64 + g * 16);

    const char* kg = (const char*)(QKV + browbase * QKVS + 512 + hh * 64);
    const char* vg = (const char*)(vT + (size_t)(b * 8 + hh) * 64 * 512);

    float m[4], s[4];
    #pragma unroll
    for (int e = 0; e < 4; ++e) { m[e] = -1e30f; s[e] = 0.f; }
    f32x4 o[4] = {};
    char* pb = sP + wid * 4096;

    for (int kt = 0; kt < 4; ++kt) {
        int k0 = kt * 128;
        // stage K tile (128 rows x 128B)
        #pragma unroll
        for (int i = 0; i < 4; ++i) {
            int row = i * 32 + (tid >> 3);
            int uu = tid & 7;
            int u0 = uu ^ (row & 7);
            gload_lds16(kg + (size_t)(k0 + row) * 3072 + u0 * 16, sK + row * 128 + uu * 16);
        }
        // stage V tile (64 d-rows x 256B k-slice)
        #pragma unroll
        for (int i = 0; i < 4; ++i) {
            int d = i * 16 + (tid >> 4);
            int uu = tid & 15;
            int u0 = uu ^ ((d & 7) << 1);
            gload_lds16(vg + (size_t)d * 1024 + k0 * 2 + u0 * 16, sV + d * 256 + uu * 16);
        }
        __syncthreads();
        // QK^T for this tile
        f32x4 sc[8];
        #pragma unroll
        for (int t2 = 0; t2 < 8; ++t2) {
            int krow = t2 * 16 + r;
            const char* kb = sK + krow * 128;
            short8v bk0 = *(const short8v*)(kb + ((g ^ (krow & 7)) * 16));
            short8v bk1 = *(const short8v*)(kb + (((4 + g) ^ (krow & 7)) * 16));
            f32x4 z = {0.f, 0.f, 0.f, 0.f};
            z = __builtin_amdgcn_mfma_f32_16x16x32_bf16(aq0, bk0, z, 0, 0, 0);
            z = __builtin_amdgcn_mfma_f32_16x16x32_bf16(aq1, bk1, z, 0, 0, 0);
            sc[t2] = z;
        }
        // online softmax update (raw-score max; 1/8 scale folded into exp)
        float tmx[4] = {-1e30f, -1e30f, -1e30f, -1e30f};
        #pragma unroll
        for (int t2 = 0; t2 < 8; ++t2)
            #pragma unroll
            for (int e = 0; e < 4; ++e) tmx[e] = fmaxf(tmx[e], sc[t2][e]);
        #pragma unroll
        for (int mm = 1; mm < 16; mm <<= 1)
            #pragma unroll
            for (int e = 0; e < 4; ++e) tmx[e] = fmaxf(tmx[e], __shfl_xor(tmx[e], mm, 64));
        float scale[4];
        #pragma unroll
        for (int e = 0; e < 4; ++e) {
            float nm = fmaxf(m[e], tmx[e]);
            scale[e] = __expf((m[e] - nm) * 0.125f);
            m[e] = nm;
        }
        float ts[4] = {0.f, 0.f, 0.f, 0.f};
        #pragma unroll
        for (int t2 = 0; t2 < 8; ++t2) {
            int k = t2 * 16 + r;
            int slot = k >> 3;
            int koff = (k & 7) * 2;
            #pragma unroll
            for (int e = 0; e < 4; ++e) {
                float pv = __expf((sc[t2][e] - m[e]) * 0.125f);
                ts[e] += pv;
                int q = g * 4 + e;
                *(unsigned short*)(pb + q * 256 + (((slot ^ (q & 7))) << 4) + koff) = f2bf(pv);
            }
        }
        #pragma unroll
        for (int mm = 1; mm < 16; mm <<= 1)
            #pragma unroll
            for (int e = 0; e < 4; ++e) ts[e] += __shfl_xor(ts[e], mm, 64);
        #pragma unroll
        for (int e = 0; e < 4; ++e) s[e] = s[e] * scale[e] + ts[e];
        #pragma unroll
        for (int dt = 0; dt < 4; ++dt)
            #pragma unroll
            for (int e = 0; e < 4; ++e) o[dt][e] *= scale[e];
        // PV for this tile (P rows are wave-private; same-wave LDS RAW is ordered)
        #pragma unroll
        for (int kc = 0; kc < 4; ++kc) {
            short8v pa = *(const short8v*)(pb + r * 256 + (((kc * 4 + g) ^ (r & 7)) << 4));
            #pragma unroll
            for (int dt = 0; dt < 4; ++dt) {
                int d = dt * 16 + r;
                short8v bv = *(const short8v*)(sV + d * 256 + (((kc * 4 + g) ^ ((d & 7) << 1)) << 4));
                o[dt] = __builtin_amdgcn_mfma_f32_16x16x32_bf16(pa, bv, o[dt], 0, 0, 0);
            }
        }
        __syncthreads();   // protect sK/sV before next stage
    }
    float inv[4];
    #pragma unroll
    for (int e = 0; e < 4; ++e) inv[e] = 1.0f / s[e];
    unsigned short* ob = O + (browbase + qbase) * 512 + hh * 64;
    #pragma unroll
    for (int dt = 0; dt < 4; ++dt)
        #pragma unroll
        for (int e = 0; e < 4; ++e)
            ob[(size_t)(g * 4 + e) * 512 + dt * 16 + r] = f2bf(o[dt][e] * inv[e]);
}

// ---------------- fused add + LayerNorm (one wave per row) ----------------
template <int PADB>
__global__ __launch_bounds__(256) void add_ln_kernel(
        const float* __restrict__ A, const float* __restrict__ R,
        const float* __restrict__ g, const float* __restrict__ bta,
        float* __restrict__ out, unsigned short* __restrict__ outb) {
    int row = blockIdx.x * 4 + (threadIdx.x >> 6);
    int lane = threadIdx.x & 63;
    const float4* a4 = (const float4*)(A + (size_t)row * DD);
    const float4* r4 = (const float4*)(R + (size_t)row * DD);
    float4 x0 = a4[lane], x1 = a4[lane + 64];
    float4 y0 = r4[lane], y1 = r4[lane + 64];
    x0.x += y0.x; x0.y += y0.y; x0.z += y0.z; x0.w += y0.w;
    x1.x += y1.x; x1.y += y1.y; x1.z += y1.z; x1.w += y1.w;
    float sum = x0.x + x0.y + x0.z + x0.w + x1.x + x1.y + x1.z + x1.w;
    #pragma unroll
    for (int mm = 1; mm < 64; mm <<= 1) sum += __shfl_xor(sum, mm, 64);
    float mean = sum * (1.f / DD);
    float d0 = x0.x - mean, d1 = x0.y - mean, d2 = x0.z - mean, d3 = x0.w - mean;
    float d4 = x1.x - mean, d5 = x1.y - mean, d6 = x1.z - mean, d7 = x1.w - mean;
    float vs = d0 * d0 + d1 * d1 + d2 * d2 + d3 * d3 + d4 * d4 + d5 * d5 + d6 * d6 + d7 * d7;
    #pragma unroll
    for (int mm = 1; mm < 64; mm <<= 1) vs += __shfl_xor(vs, mm, 64);
    float rstd = rsqrtf(vs * (1.f / DD) + EPSV);
    float4 g0 = ((const float4*)g)[lane], g1 = ((const float4*)g)[lane + 64];
    float4 b0 = ((const float4*)bta)[lane], b1 = ((const float4*)bta)[lane + 64];
    float4 z0, z1;
    z0.x = d0 * rstd * g0.x + b0.x; z0.y = d1 * rstd * g0.y + b0.y;
    z0.z = d2 * rstd * g0.z + b0.z; z0.w = d3 * rstd * g0.w + b0.w;
    z1.x = d4 * rstd * g1.x + b1.x; z1.y = d5 * rstd * g1.y + b1.y;
    z1.z = d6 * rstd * g1.z + b1.z; z1.w = d7 * rstd * g1.w + b1.w;
    float* op = out + (size_t)row * DD;
    *(float4*)(op + lane * 4) = z0;
    *(float4*)(op + 256 + lane * 4) = z1;
    size_t rowb = PADB ? (size_t)row + (row >> 9) : (size_t)row;
    unsigned short* ob = outb + rowb * DD;
    ushort4 u0, u1;
    u0.x = f2bf(z0.x); u0.y = f2bf(z0.y); u0.z = f2bf(z0.z); u0.w = f2bf(z0.w);
    u1.x = f2bf(z1.x); u1.y = f2bf(z1.y); u1.z = f2bf(z1.z); u1.w = f2bf(z1.w);
    *(ushort4*)(ob + lane * 4) = u0;
    *(ushort4*)(ob + 256 + lane * 4) = u1;
}

// ---------------- host launch ----------------
extern "C" void kernel_launch(void* const* d_in, const int* in_sizes, int n_in,
                              void* d_out, int out_size, void* d_ws, size_t ws_size,
                              hipStream_t stream) {
    const float* x      = (const float*)d_in[0];
    const float* convW0 = (const float*)d_in[1];
    const float* convb0 = (const float*)d_in[2];
    const float* gn0_g  = (const float*)d_in[3];
    const float* gn0_b  = (const float*)d_in[4];
    const float* convW1 = (const float*)d_in[5];
    const float* convb1 = (const float*)d_in[6];
    const float* gn1_g  = (const float*)d_in[7];
    const float* gn1_b  = (const float*)d_in[8];
    const float* Wq     = (const float*)d_in[9];
    const float* Wk     = (const float*)d_in[10];
    const float* Wv     = (const float*)d_in[11];
    const float* Wo     = (const float*)d_in[12];
    const float* W1     = (const float*)d_in[13];
    const float* b1     = (const float*)d_in[14];
    const float* W2     = (const float*)d_in[15];
    const float* b2     = (const float*)d_in[16];
    const float* ln1_g  = (const float*)d_in[17];
    const float* ln1_b  = (const float*)d_in[18];
    const float* ln2_g  = (const float*)d_in[19];
    const float* ln2_b  = (const float*)d_in[20];
    const float* Wd     = (const float*)d_in[21];
    const float* bd     = (const float*)d_in[22];

    const int M = BB * SS;                       // 8192
    const size_t NBUF = (size_t)M * DD;          // 4,194,304

    // ---- workspace layout ----
    char* p = (char*)d_ws;
    auto alloc = [&](size_t bytes) { char* q = p; p += (bytes + 255) & ~(size_t)255; return q; };
    float* h   = (float*)alloc(NBUF * 4);
    float* hk  = (float*)alloc(NBUF * 4);
    float* bo  = (float*)alloc(NBUF * 4);
    float* bf2 = bo;
    char* S1 = alloc((size_t)M * FFD * 2);                    // 32MB shared region
    unsigned short* bqkv16 = (unsigned short*)S1;
    unsigned short* vTb    = (unsigned short*)(S1 + (size_t)M * QKVS * 2);
    unsigned short* ffb    = (unsigned short*)S1;
    unsigned short* hb  = (unsigned short*)alloc((size_t)BB * 513 * 512 * 2);
    unsigned short* hkb = (unsigned short*)alloc(NBUF * 2);
    unsigned short* bab = hkb;
    unsigned short* xT  = (unsigned short*)alloc((size_t)BB * 1038 * 64 * 2);
    unsigned short* c1in = (unsigned short*)alloc((size_t)BB * 514 * 512 * 2);
    float* c0out = (float*)alloc(NBUF * 4);
    float* c1out = c0out;
    float2* gstats = (float2*)alloc((size_t)BB * 256 * 8);
    unsigned short* wqkvb = (unsigned short*)alloc((size_t)NL * QKVS * DD * 2);
    unsigned short* wob   = (unsigned short*)alloc((size_t)NL * DD * DD * 2);
    unsigned short* w1b   = (unsigned short*)alloc((size_t)NL * FFD * DD * 2);
    unsigned short* w2b   = (unsigned short*)alloc((size_t)NL * DD * FFD * 2);
    unsigned short* wc1   = (unsigned short*)alloc((size_t)DD * 1536 * 2);
    unsigned short* wc0   = (unsigned short*)alloc((size_t)DD * 960 * 2);
    unsigned short* wdc   = (unsigned short*)alloc((size_t)128 * 1024 * 2);

    // ---- weight prep ----
    {
        int seg4 = DD * DD / 4, ostr4 = QKVS * DD / 4;
        int blks = NL * seg4 / 256;
        cvt_bf16_seg_kernel<<<blks, 256, 0, stream>>>(Wq, wqkvb, seg4, ostr4);
        cvt_bf16_seg_kernel<<<blks, 256, 0, stream>>>(Wk, wqkvb + (size_t)DD * DD, seg4, ostr4);
        cvt_bf16_seg_kernel<<<blks, 256, 0, stream>>>(Wv, wqkvb + (size_t)2 * DD * DD, seg4, ostr4);
        cvt_bf16_kernel<<<NL * DD * DD / 1024, 256, 0, stream>>>(Wo, wob);
        cvt_bf16_kernel<<<NL * FFD * DD / 1024, 256, 0, stream>>>(W1, w1b);
        cvt_bf16_kernel<<<NL * DD * FFD / 1024, 256, 0, stream>>>(W2, w2b);
        reorder_wc1<<<DD * 1536 / 256, 256, 0, stream>>>(convW1, wc1);
        reorder_wc0<<<DD * 960 / 256, 256, 0, stream>>>(convW0, wc0);
        reorder_wdc<<<128 * 1024 / 256, 256, 0, stream>>>(Wd, wdc);
        zero_pads<<<BB, 256, 0, stream>>>(xT, c1in, hb);
    }

    // ---- conv encoder ----
    transpose_pad<<<dim3(TT / 64, 1, BB), 256, 0, stream>>>(x, xT, CIN, TT, 7);
    gemm_mfma<1, 2, 1><<<dim3(4, 64), 256, 0, stream>>>(
        xT, wc0, convb0, c0out, nullptr, M, DD, 960, 128, 896);
    gn_stats_kernel<<<BB * 256 / 4, 256, 0, stream>>>(c0out, gstats);
    gn_apply_kernel<0><<<dim3(8, 8, BB), 256, 0, stream>>>(
        c0out, gstats, gn0_g, gn0_b, nullptr, c1in, 514, 1);
    gemm_mfma<1, 2, 1><<<dim3(4, 64), 256, 0, stream>>>(
        c1in, wc1, convb1, c1out, nullptr, M, DD, 1536, 512, 1024);
    gn_stats_kernel<<<BB * 256 / 4, 256, 0, stream>>>(c1out, gstats);
    gn_apply_kernel<1><<<dim3(8, 8, BB), 256, 0, stream>>>(
        c1out, gstats, gn1_g, gn1_b, h, hb, 513, 0);

    // ---- transformer ----
    for (int l = 0; l < NL; ++l) {
        const unsigned short* wqkv_l = wqkvb + (size_t)l * QKVS * DD;
        const unsigned short* wo_l   = wob + (size_t)l * DD * DD;
        const unsigned short* w1_l   = w1b + (size_t)l * FFD * DD;
        const unsigned short* w2_l   = w2b + (size_t)l * DD * FFD;

        gemm_mfma<0, 3, 0><<<dim3(QKVS / 128, 64), 256, 0, stream>>>(
            hb, wqkv_l, nullptr, bqkv16, vTb, M, QKVS, DD, 512, 512);
        attn_flash<<<dim3(8, NHEAD, BB), 256, 0, stream>>>(bqkv16, vTb, bab);
        gemm_mfma<0, 0, 1><<<dim3(4, 64), 256, 0, stream>>>(
            bab, wo_l, nullptr, bo, nullptr, M, DD, DD, 512, 0);
        add_ln_kernel<0><<<M / 4, 256, 0, stream>>>(
            bo, h, ln1_g + (size_t)l * DD, ln1_b + (size_t)l * DD, hk, hkb);
        gemm_mfma<2, 1, 0><<<dim3(FFD / 128, 64), 256, 0, stream>>>(
            hkb, w1_l, b1 + (size_t)l * FFD, ffb, nullptr, M, FFD, DD, 512, 0);
        gemm_mfma<1, 0, 1><<<dim3(4, 64), 256, 0, stream>>>(
            ffb, w2_l, b2 + (size_t)l * DD, bf2, nullptr, M, DD, FFD, 2048, 0);
        add_ln_kernel<1><<<M / 4, 256, 0, stream>>>(
            bf2, hk, ln2_g + (size_t)l * DD, ln2_b + (size_t)l * DD, h, hb);
    }

    // ---- deconv decoder ----
    gemm_mfma<1, 4, 1><<<dim3(1, 64), 256, 0, stream>>>(
        hb, wdc, bd, (float*)d_out, nullptr, M, 128, 1024, 512, 512);
}